// Round 2
// 404.016 us; speedup vs baseline: 1.0285x; 1.0285x over previous
//
#include <hip/hip_runtime.h>

// HomologicalConnectivityLoss: adj (8192x8192 fp32, bit-exact symmetric).
// loss = (n_comp-1)^2 + max(0, n_edges - N + n_comp)^2
//
// Ladder:
//  R1 767us: fused global union-find (pointer-chase poison).
//  R2 1553us: per-edge global atomicAdd append + global union-find.
//  R3 437us: LDS edge staging + single-block LDS union-find.
//  R4 415us: SV min-label propagation in LDS; scan 4-loads-in-flight
//            (but only for rows >3072 — tail loop is 1-in-flight).
//  R5 (this, resubmit — R5 bench was an infra failure, kernel never ran):
//    scan: row-pair unified into one virtual index space; all 9 float4
//          loads per thread issued before processing (9-deep MLP, no
//          serialized tail loop). Triangle read = 134 MB -> ~25-40us.
//    label: 8-deep register prefetch of edges per relax batch; double
//          pointer-jump shortcut per round.
//
// Workspace (ints): ws[0]=lower-edge count, ws[1]=diag count,
// ws[2..] = edge buffer (u32 encoded (r<<13)|j, r>j).

#define NN 8192
#define SCAN_LDS_CAP 2048   // expected ~19 edges/block; huge margin

__global__ __launch_bounds__(64) void init_kernel(int* counters) {
    if (threadIdx.x < 2) counters[threadIdx.x] = 0;
}

// Block b processes rows b and NN-1-b (cols 0..r): balanced triangle scan.
// The two rows form one virtual float4 index space of 2049-2050 entries ->
// exactly 9 per thread at 256 threads. All 9 loads are issued back-to-back
// (independent, predicated) before any processing: 9-deep MLP per thread.
__global__ __launch_bounds__(256) void scan_kernel(const float* __restrict__ adj,
                                                   int* __restrict__ counters,
                                                   unsigned int* __restrict__ ebuf,
                                                   int cap) {
    __shared__ int lds_n;
    __shared__ int lds_base;
    __shared__ unsigned int lds_e[SCAN_LDS_CAP];
    if (threadIdx.x == 0) lds_n = 0;
    __syncthreads();

    int b = blockIdx.x;
    int ra = b;
    int rb = NN - 1 - b;
    int nfa = (ra + 4) >> 2;          // ceil((ra+1)/4)
    int nfb = (rb + 4) >> 2;
    int tot = nfa + nfb;              // always 2049 or 2050 (<= 9*256)

    int t = threadIdx.x;
    int c1 = 0;                       // diagonal positives

    float4 v[9];
    int   rr[9];
    int   gg[9];
    bool  ok[9];

    // issue phase: 9 independent loads in flight
    #pragma unroll
    for (int k = 0; k < 9; ++k) {
        int vg = t + (k << 8);
        ok[k] = vg < tot;
        bool inA = vg < nfa;
        int r = inA ? ra : rb;
        int g = inA ? vg : vg - nfa;
        rr[k] = r;
        gg[k] = g;
        if (ok[k]) v[k] = ((const float4*)(adj + (size_t)r * NN))[g];
    }

    // process phase
    #pragma unroll
    for (int k = 0; k < 9; ++k) {
        if (!ok[k]) continue;
        int r  = rr[k];
        int j0 = gg[k] << 2;
        float vv[4] = {v[k].x, v[k].y, v[k].z, v[k].w};
        #pragma unroll
        for (int c = 0; c < 4; ++c) {
            int j = j0 + c;
            bool pos = vv[c] > 0.0f;
            if (pos && j < r) {
                int kk = atomicAdd(&lds_n, 1);   // LDS atomic: CU-local
                unsigned int e = ((unsigned)r << 13) | (unsigned)j;
                if (kk < SCAN_LDS_CAP) lds_e[kk] = e;
                else {  // never taken in practice; correctness fallback
                    int gk = atomicAdd(counters, 1);
                    if (gk < cap) ebuf[gk] = e;
                }
            }
            c1 += (pos && j == r) ? 1 : 0;
        }
    }

    // diag count: wave reduce, one atomic per wave
    #pragma unroll
    for (int off = 32; off > 0; off >>= 1) c1 += __shfl_down(c1, off, 64);
    if ((t & 63) == 0 && c1) atomicAdd(counters + 1, c1);

    __syncthreads();
    int n = lds_n < SCAN_LDS_CAP ? lds_n : SCAN_LDS_CAP;
    if (t == 0) lds_base = atomicAdd(counters, n);  // 1 global atomic per block
    __syncthreads();
    int base = lds_base;
    for (int k = t; k < n; k += 256) {
        int idx = base + k;
        if (idx < cap) ebuf[idx] = lds_e[k];
    }
}

// Single block: min-label propagation over the compact edge list, labels in
// LDS. Relax pass: edges prefetched 8-deep into registers (8 independent
// global loads in flight -> L2 latency hidden), then 2 independent LDS
// atomicMins per edge. Shortcut: two pointer-jumping passes per round
// (lab[i]=lab[lab[i]]; sound: labels are node indices of the SAME component
// and only decrease; races are monotone-benign on aligned 32-bit words).
// Fixpoint: exactly one node per component keeps lab[i]==i (the min).
__global__ __launch_bounds__(1024) void label_final_kernel(
        const unsigned int* __restrict__ ebuf,
        const int* __restrict__ counters,
        int cap, float* __restrict__ out) {
    __shared__ int lab[NN];          // 32 KB
    __shared__ int changed;
    __shared__ int wsum[16];
    int tid = threadIdx.x;
    for (int i = tid; i < NN; i += 1024) lab[i] = i;
    __syncthreads();

    int total_lower = counters[0];
    int m = total_lower < cap ? total_lower : cap;

    for (;;) {
        if (tid == 0) changed = 0;
        __syncthreads();

        // relax: 8-deep prefetch, then push smaller endpoint label to larger
        for (int base = tid; base < m; base += 8192) {
            unsigned int e[8];
            bool val[8];
            #pragma unroll
            for (int q = 0; q < 8; ++q) {
                int idx = base + (q << 10);
                val[q] = idx < m;
                if (val[q]) e[q] = ebuf[idx];
            }
            #pragma unroll
            for (int q = 0; q < 8; ++q) {
                if (!val[q]) continue;
                int r = (int)(e[q] >> 13);
                int j = (int)(e[q] & (NN - 1));
                int lr = lab[r];
                int lj = lab[j];
                if (lj < lr) {
                    int old = atomicMin(&lab[r], lj);
                    if (lj < old) changed = 1;
                } else if (lr < lj) {
                    int old = atomicMin(&lab[j], lr);
                    if (lr < old) changed = 1;
                }
            }
        }
        __syncthreads();

        // shortcut: two pointer-jumping passes (monotone, benign races)
        #pragma unroll
        for (int s = 0; s < 2; ++s) {
            for (int i = tid; i < NN; i += 1024) {
                int l = lab[i];
                int ll = lab[l];
                if (ll < l) { lab[i] = ll; changed = 1; }
            }
        }
        __syncthreads();

        if (changed == 0) break;   // uniform decision (post-barrier read)
        __syncthreads();           // protect next round's reset vs this read
    }

    // count self-labeled nodes = component count
    int cnt = 0;
    for (int i = tid; i < NN; i += 1024) cnt += (lab[i] == i) ? 1 : 0;
    #pragma unroll
    for (int off = 32; off > 0; off >>= 1) cnt += __shfl_down(cnt, off, 64);
    if ((tid & 63) == 0) wsum[tid >> 6] = cnt;
    __syncthreads();
    if (tid == 0) {
        int roots = 0;
        #pragma unroll
        for (int w = 0; w < 16; ++w) roots += wsum[w];
        long long total = 2LL * (long long)total_lower + (long long)counters[1];
        long long n_edges_i = total >> 1;               // exact integer // 2
        double n_comp = (double)roots;
        double comp_loss = (n_comp - 1.0) * (n_comp - 1.0);
        double betti = (double)n_edges_i - (double)NN + n_comp;
        double cyc = betti > 0.0 ? betti : 0.0;
        out[0] = (float)(comp_loss + cyc * cyc);
    }
}

extern "C" void kernel_launch(void* const* d_in, const int* in_sizes, int n_in,
                              void* d_out, int out_size, void* d_ws, size_t ws_size,
                              hipStream_t stream) {
    const float* adj = (const float*)d_in[0];
    int* ws = (int*)d_ws;
    int* counters = ws;                       // [0]=lower edges, [1]=diag
    unsigned int* ebuf = (unsigned int*)(ws + 2);
    long long cap_ll = (long long)(ws_size / 4) - 2;
    int cap = cap_ll > 0x7fffffff ? 0x7fffffff : (cap_ll < 0 ? 0 : (int)cap_ll);
    float* out = (float*)d_out;

    init_kernel<<<1, 64, 0, stream>>>(counters);
    scan_kernel<<<NN / 2, 256, 0, stream>>>(adj, counters, ebuf, cap);
    label_final_kernel<<<1, 1024, 0, stream>>>(ebuf, counters, cap, out);
}